// Round 6
// baseline (206.023 us; speedup 1.0000x reference)
//
#include <hip/hip_runtime.h>
#include <hip/hip_bf16.h>

namespace {
enum : int {
  CIN = 64, CMID = 32, COUT = 64,
  H = 128, W = 48, HW = H * W,          // 6144
  HPF = 144, WPF = 64,
  KPSZ = CMID * HPF * WPF,              // 294912 floats
  QSSZ = CMID * HW,                     // 196608 floats
  // attention tiling
  QPT = 6,                              // queries per lane
  QG  = 64 * QPT,                       // 384 queries per block
  NQG = 8,                              // 3072/384 query groups per n
  KVW = 180,                            // kv elems per wave
  SG  = 8,                              // slice groups along kv (8*4*180=5760)
  PARTSZ = 16 * NQG * SG * QG * 5,      // 1,966,080 floats
  CIGQ = 4,                             // qkv conv ci split (16 ci each)
  CIGO = 4,                             // out conv ci split (8 ci each)
};
}

__device__ __forceinline__ float fexp2(float x) { return __builtin_amdgcn_exp2f(x); }

// ---------------------------------------------------------------------------
// Kernel 1: q/k/v 3x3 convs (64->32 ch), ci split 4-ways, weights staged in
// LDS (coalesced coop load; inner loop reads LDS broadcast, no global weight
// loads). Non-atomic partial planes. grid (128 y, 2 half, 4 cig) x 192.
// ---------------------------------------------------------------------------
__global__ __launch_bounds__(192) void qkv_conv_kernel(
    const float* __restrict__ x,
    const float* __restrict__ wq, const float* __restrict__ wk,
    const float* __restrict__ wv, float* __restrict__ qpart)
{
  __shared__ float ws[48 * 144];                 // 27648 B
  __shared__ alignas(16) float xs[3 * 16 * 52];  // 9984 B
  const int y = blockIdx.x;
  const int half = blockIdx.y;
  const int cig = blockIdx.z;          // 16 ci per group
  const int tid = threadIdx.x;
  for (int idx = tid; idx < 3 * 16 * 50; idx += 192) {
    int ky = idx / (16 * 50);
    int r = idx - ky * (16 * 50);
    int cil = r / 50;
    int xx = r - cil * 50;
    int gy = y + ky - 1;
    int gx = xx - 1;
    float v = 0.0f;
    if (gy >= 0 && gy < H && (unsigned)gx < (unsigned)W)
      v = x[(cig * 16 + cil) * HW + gy * W + gx];
    xs[(ky * 16 + cil) * 52 + xx] = v;
  }
  // stage weights: this block's 48 cogs x (16 ci x 9 taps)
  for (int idx = tid; idx < 48 * 144; idx += 192) {
    const int cl_loc = idx / 144;
    const int e = idx - cl_loc * 144;     // ci_local*9 + tap (contiguous)
    const int cog = half * 48 + cl_loc;
    const int t = cog >> 5;
    const int cl = cog & 31;
    const float* wsel = (t == 0) ? wq : (t == 1) ? wk : wv;
    ws[idx] = wsel[cl * (CIN * 9) + cig * 144 + e];
  }
  __syncthreads();

  const int col = tid >> 2;        // 0..47
  const int xg = tid & 3;          // 0..3
  const int cog = half * 48 + col;
  const float* wrowb = &ws[col * 144];

  float acc[12];
#pragma unroll
  for (int i = 0; i < 12; ++i) acc[i] = 0.0f;

#pragma unroll 4
  for (int cil = 0; cil < 16; ++cil) {
#pragma unroll
    for (int ky = 0; ky < 3; ++ky) {
      const float* xb = &xs[(ky * 16 + cil) * 52 + xg * 12];
      const float4* p4 = reinterpret_cast<const float4*>(xb);
      float4 r0 = p4[0], r1 = p4[1], r2 = p4[2];
      float xr[14] = {r0.x, r0.y, r0.z, r0.w, r1.x, r1.y, r1.z, r1.w,
                      r2.x, r2.y, r2.z, r2.w, xb[12], xb[13]};
      const float* wr = wrowb + cil * 9 + ky * 3;
#pragma unroll
      for (int kx = 0; kx < 3; ++kx) {
        float wgt = wr[kx];
#pragma unroll
        for (int xx = 0; xx < 12; ++xx)
          acc[xx] = fmaf(wgt, xr[xx + kx], acc[xx]);
      }
    }
  }

  const int x0 = xg * 12;
  float* dst = &qpart[(size_t)(cig * 96 + cog) * HW + y * W + x0];
#pragma unroll
  for (int xx = 0; xx < 12; ++xx) dst[xx] = acc[xx];
}

// ---------------------------------------------------------------------------
// Kernel 1b: reduce 4 ci-partials, apply bias (+ exp2-domain scale for q),
// scatter into q_s / flange-padded kp,vp. float4 per thread.
// ---------------------------------------------------------------------------
__global__ __launch_bounds__(256) void qkv_reduce_kernel(
    const float* __restrict__ qpart,
    const float* __restrict__ bq, const float* __restrict__ bk,
    const float* __restrict__ bv,
    float* __restrict__ q_s, float* __restrict__ kp, float* __restrict__ vp)
{
  const int fidx = blockIdx.x * 256 + threadIdx.x;  // 0..147455 (96ch*1536)
  const int cog = fidx / 1536;
  const int p4 = fidx - cog * 1536;
  const float4* src = reinterpret_cast<const float4*>(qpart) + cog * 1536 + p4;
  float4 s = src[0];
  const float4 s1 = src[96 * 1536], s2 = src[2 * 96 * 1536], s3 = src[3 * 96 * 1536];
  s.x += s1.x + s2.x + s3.x;
  s.y += s1.y + s2.y + s3.y;
  s.z += s1.z + s2.z + s3.z;
  s.w += s1.w + s2.w + s3.w;

  const int pix = p4 * 4;
  const int y = pix / W;
  const int x = pix - y * W;
  if (cog < 32) {
    const float b = bq[cog];
    const float c = 0.7213475204444817f;   // 0.5 * log2(e)
    float4 o = {(s.x + b) * c, (s.y + b) * c, (s.z + b) * c, (s.w + b) * c};
    reinterpret_cast<float4*>(q_s)[cog * 1536 + p4] = o;
  } else {
    const int cl = cog & 31;
    const float b = (cog < 64) ? bk[cl] : bv[cl];
    float* dst = (cog < 64) ? kp : vp;
    float4 o = {s.x + b, s.y + b, s.z + b, s.w + b};
    *reinterpret_cast<float4*>(&dst[cl * (HPF * WPF) + (y + 8) * WPF + (x + 8)]) = o;
  }
}

// ---------------------------------------------------------------------------
// Kernel 2: blocked local attention, scalar fp32, exp2-domain softmax with
// fixed bias (additive partials). grid (8 qgrp, 8 sgrp, 16 n) x 256.
// Explicit next-iter k4/v4 register prefetch hides LDS latency behind the
// 6-query compute body. Non-atomic partial output.
// ---------------------------------------------------------------------------
__global__ __launch_bounds__(256, 4) void attn_kernel(
    const float* __restrict__ q_s, const float* __restrict__ kp,
    const float* __restrict__ vp, float* __restrict__ part)
{
  __shared__ alignas(16) float smem[4 * QG * 5];   // 30720 B (>= tiles 23040)
  float4* tiles = reinterpret_cast<float4*>(smem); // [4][2][KVW]

  const int tid = threadIdx.x;
  const int lane = tid & 63;
  const int w = tid >> 6;
  const int qgrp = blockIdx.x;   // 0..7
  const int sgrp = blockIdx.y;   // 0..7
  const int n = blockIdx.z;      // 0..15
  const int h = n >> 1;
  const int j = n & 1;

  float qr[QPT][4];
#pragma unroll
  for (int qi = 0; qi < QPT; ++qi) {
    const int qg = qgrp * QG + qi * 64 + lane;
    const int q0 = qg / 24;
    const int q1 = qg - q0 * 24;
    const int qoff = q0 * W + j * 24 + q1;
#pragma unroll
    for (int d = 0; d < 4; ++d)
      qr[qi][d] = q_s[(h * 4 + d) * HW + qoff];
  }

  // flat-gather base reproducing torch.as_strided semantics
  const int gbase = h * 24576 + j * 24;
  const int mbase = (sgrp * 4 + w) * KVW;

  float4* tk = tiles + (w * 2 + 0) * KVW;
  float4* tv = tiles + (w * 2 + 1) * KVW;
  for (int mt = lane; mt < KVW; mt += 64) {
    const int m = mbase + mt;
    const int m0 = m / 40;
    const int m1 = m - m0 * 40;
    const int off = gbase + m0 * 48 + m1;
    float4 kk, vv;
    kk.x = kp[off];
    kk.y = kp[off + 6144];
    kk.z = kp[off + 12288];
    kk.w = kp[off + 18432];
    vv.x = vp[off];
    vv.y = vp[off + 6144];
    vv.z = vp[off + 12288];
    vv.w = vp[off + 18432];
    tk[mt] = kk;
    tv[mt] = vv;
  }
  asm volatile("s_waitcnt vmcnt(0) lgkmcnt(0)" ::: "memory");

  float lsum[QPT];
  float4 acc[QPT];
#pragma unroll
  for (int qi = 0; qi < QPT; ++qi) {
    lsum[qi] = 0.0f;
    acc[qi] = make_float4(0.0f, 0.0f, 0.0f, 0.0f);
  }

  auto step = [&](const float4& k4, const float4& v4) {
#pragma unroll
    for (int qi = 0; qi < QPT; ++qi) {
      float s = fmaf(qr[qi][0], k4.x,
                fmaf(qr[qi][1], k4.y,
                fmaf(qr[qi][2], k4.z,
                fmaf(qr[qi][3], k4.w, -16.0f))));
      const float p = fexp2(s);
      lsum[qi] += p;
      acc[qi].x = fmaf(p, v4.x, acc[qi].x);
      acc[qi].y = fmaf(p, v4.y, acc[qi].y);
      acc[qi].z = fmaf(p, v4.z, acc[qi].z);
      acc[qi].w = fmaf(p, v4.w, acc[qi].w);
    }
  };

  float4 k4 = tk[0];
  float4 v4 = tv[0];
#pragma unroll 4
  for (int mt = 0; mt < KVW - 1; ++mt) {
    const float4 kn = tk[mt + 1];   // prefetch next pair; waitcnt lands
    const float4 vn = tv[mt + 1];   // behind this iteration's compute
    step(k4, v4);
    k4 = kn;
    v4 = vn;
  }
  step(k4, v4);

  // in-block merge: 4 waves -> 1 partial set (non-atomic global write)
  __syncthreads();   // done reading tiles; smem becomes merge buffer
#pragma unroll
  for (int qi = 0; qi < QPT; ++qi) {
    float* mb = &smem[w * (QG * 5) + qi * 5 * 64 + lane];
    mb[0]   = lsum[qi];
    mb[64]  = acc[qi].x;
    mb[128] = acc[qi].y;
    mb[192] = acc[qi].z;
    mb[256] = acc[qi].w;
  }
  __syncthreads();
  float* pout = part + (size_t)((n * NQG + qgrp) * SG + sgrp) * (QG * 5);
  for (int id = tid; id < QG * 5; id += 256)
    pout[id] = smem[id] + smem[QG * 5 + id] + smem[2 * QG * 5 + id] +
               smem[3 * QG * 5 + id];
}

// ---------------------------------------------------------------------------
// Kernel 2b: merge SG slice-group partials + normalize -> o_mid.
// grid (NQG, 16) x 384 threads; thread = one query.
// ---------------------------------------------------------------------------
__global__ __launch_bounds__(384) void merge_kernel(
    const float* __restrict__ part, float* __restrict__ o_mid)
{
  const int tid = threadIdx.x;
  const int qi = tid >> 6;
  const int lane = tid & 63;
  const int qgrp = blockIdx.x;
  const int n = blockIdx.y;
  const int h = n >> 1;
  const int j = n & 1;

  const float* pb = part + (size_t)((n * NQG + qgrp) * SG) * (QG * 5) +
                    qi * 5 * 64 + lane;
  float L = 0.0f, A0 = 0.0f, A1 = 0.0f, A2 = 0.0f, A3 = 0.0f;
#pragma unroll
  for (int s = 0; s < SG; ++s) {
    const float* p = pb + s * (QG * 5);
    L  += p[0];
    A0 += p[64];
    A1 += p[128];
    A2 += p[192];
    A3 += p[256];
  }
  const float inv = 1.0f / L;
  const int qg = qgrp * QG + qi * 64 + lane;
  const int q0 = qg / 24;
  const int q1 = qg - q0 * 24;
  const int qoff = q0 * W + j * 24 + q1;
  o_mid[(h * 4 + 0) * HW + qoff] = A0 * inv;
  o_mid[(h * 4 + 1) * HW + qoff] = A1 * inv;
  o_mid[(h * 4 + 2) * HW + qoff] = A2 * inv;
  o_mid[(h * 4 + 3) * HW + qoff] = A3 * inv;
}

// ---------------------------------------------------------------------------
// Kernel 3: output 3x3 conv (32->64 ch), ci split 4-ways, weights in LDS,
// non-atomic partials. grid (128 y, 2 half, 4 cig) x 128 threads.
// ---------------------------------------------------------------------------
__global__ __launch_bounds__(128) void out_conv_kernel(
    const float* __restrict__ o_mid, const float* __restrict__ wo,
    float* __restrict__ opart)
{
  __shared__ float ws[32 * 72];                  // 9216 B
  __shared__ alignas(16) float xs[3 * 8 * 52];   // 4992 B
  const int y = blockIdx.x;
  const int half = blockIdx.y;
  const int cig = blockIdx.z;          // 8 ci per group
  const int tid = threadIdx.x;
  for (int idx = tid; idx < 3 * 8 * 50; idx += 128) {
    int ky = idx / (8 * 50);
    int r = idx - ky * (8 * 50);
    int cil = r / 50;
    int xx = r - cil * 50;
    int gy = y + ky - 1;
    int gx = xx - 1;
    float v = 0.0f;
    if (gy >= 0 && gy < H && (unsigned)gx < (unsigned)W)
      v = o_mid[(cig * 8 + cil) * HW + gy * W + gx];
    xs[(ky * 8 + cil) * 52 + xx] = v;
  }
  for (int idx = tid; idx < 32 * 72; idx += 128) {
    const int co_loc = idx / 72;
    const int e = idx - co_loc * 72;
    ws[idx] = wo[(half * 32 + co_loc) * (CMID * 9) + cig * 72 + e];
  }
  __syncthreads();

  const int col = tid >> 2;
  const int xg = tid & 3;
  const int co = half * 32 + col;
  const float* wrowb = &ws[col * 72];
  float acc[12];
#pragma unroll
  for (int i = 0; i < 12; ++i) acc[i] = 0.0f;

#pragma unroll 2
  for (int cil = 0; cil < 8; ++cil) {
#pragma unroll
    for (int ky = 0; ky < 3; ++ky) {
      const float* xb = &xs[(ky * 8 + cil) * 52 + xg * 12];
      const float4* p4 = reinterpret_cast<const float4*>(xb);
      float4 r0 = p4[0], r1 = p4[1], r2 = p4[2];
      float xr[14] = {r0.x, r0.y, r0.z, r0.w, r1.x, r1.y, r1.z, r1.w,
                      r2.x, r2.y, r2.z, r2.w, xb[12], xb[13]};
      const float* wr = wrowb + cil * 9 + ky * 3;
#pragma unroll
      for (int kx = 0; kx < 3; ++kx) {
        float wgt = wr[kx];
#pragma unroll
        for (int xx = 0; xx < 12; ++xx)
          acc[xx] = fmaf(wgt, xr[xx + kx], acc[xx]);
      }
    }
  }

  const int x0 = xg * 12;
  float* dst = &opart[(size_t)(cig * 64 + co) * HW + y * W + x0];
#pragma unroll
  for (int xx = 0; xx < 12; ++xx) dst[xx] = acc[xx];
}

// ---------------------------------------------------------------------------
// Kernel 3b: reduce 4 out-conv partials -> final output. float4 per thread.
// ---------------------------------------------------------------------------
__global__ __launch_bounds__(256) void out_reduce_kernel(
    const float* __restrict__ opart, float* __restrict__ out)
{
  const int fidx = blockIdx.x * 256 + threadIdx.x;  // 0..98303 (64ch*1536)
  const float4* src = reinterpret_cast<const float4*>(opart) + fidx;
  float4 s = src[0];
  const float4 s1 = src[64 * 1536], s2 = src[2 * 64 * 1536], s3 = src[3 * 64 * 1536];
  s.x += s1.x + s2.x + s3.x;
  s.y += s1.y + s2.y + s3.y;
  s.z += s1.z + s2.z + s3.z;
  s.w += s1.w + s2.w + s3.w;
  reinterpret_cast<float4*>(out)[fidx] = s;
}

// ---------------------------------------------------------------------------
extern "C" void kernel_launch(void* const* d_in, const int* in_sizes, int n_in,
                              void* d_out, int out_size, void* d_ws, size_t ws_size,
                              hipStream_t stream) {
  const float* x  = (const float*)d_in[0];
  const float* wq = (const float*)d_in[1];
  const float* bq = (const float*)d_in[2];
  const float* wk = (const float*)d_in[3];
  const float* bk = (const float*)d_in[4];
  const float* wv = (const float*)d_in[5];
  const float* bv = (const float*)d_in[6];
  const float* wo = (const float*)d_in[7];
  float* out = (float*)d_out;

  // ws layout (floats):
  // q_s[196608] | kp[294912] | vp[294912] | o_mid[196608] | apart[1966080]
  // | qpart[2359296] (opart aliases qpart - phases are stream-ordered)
  float* q_s   = (float*)d_ws;
  float* kp    = q_s + QSSZ;
  float* vp    = kp + KPSZ;
  float* o_mid = vp + KPSZ;
  float* apart = o_mid + QSSZ;
  float* qpart = apart + PARTSZ;
  float* opart = qpart;

  // zero only the flange padding regions of kp/vp (interiors fully written)
  hipMemsetAsync((void*)kp, 0, (size_t)(2 * KPSZ) * sizeof(float), stream);

  qkv_conv_kernel<<<dim3(128, 2, CIGQ), 192, 0, stream>>>(x, wq, wk, wv, qpart);
  qkv_reduce_kernel<<<dim3(576), 256, 0, stream>>>(qpart, bq, bk, bv,
                                                   q_s, kp, vp);
  attn_kernel<<<dim3(NQG, SG, 16), 256, 0, stream>>>(q_s, kp, vp, apart);
  merge_kernel<<<dim3(NQG, 16), 384, 0, stream>>>(apart, o_mid);
  out_conv_kernel<<<dim3(128, 2, CIGO), 128, 0, stream>>>(o_mid, wo, opart);
  out_reduce_kernel<<<dim3(384), 256, 0, stream>>>(opart, out);
}

// Round 8
// 194.755 us; speedup vs baseline: 1.0579x; 1.0579x over previous
//
#include <hip/hip_runtime.h>
#include <hip/hip_bf16.h>

typedef float f32x2 __attribute__((ext_vector_type(2)));

namespace {
enum : int {
  CIN = 64, CMID = 32, COUT = 64,
  H = 128, W = 48, HW = H * W,          // 6144
  QSSZ = CMID * HW,                     // 196608 floats
  // attention tiling
  QPT = 4,                              // queries per lane (2 f32x2 pairs)
  QG  = 64 * QPT,                       // 256 queries per block
  NQG = 12,                             // 3072/256 query groups per n
  KVW = 180,                            // kv elems per wave
  SG  = 8,                              // slice groups along kv (8*4*180=5760)
  KVLEN = 5760,
  PARTSZ = 16 * NQG * SG * QG * 5,      // 1,966,080 floats
  KVISZ = 16 * KVLEN * 8,               // 737,280 floats (packed k4|v4)
  CIGQ = 4, CIGO = 4,
};
}

__device__ __forceinline__ float fexp2(float x) { return __builtin_amdgcn_exp2f(x); }

// ---------------------------------------------------------------------------
// Kernel 1: q/k/v 3x3 convs (64->32 ch), ci split 4-ways, weights staged in
// LDS with stride 145 (bank-conflict-free: (col*145+e)%32 spreads over all
// banks; stride 144 mapped 48 cols onto 2 banks). grid (128,2,4) x 192.
// ---------------------------------------------------------------------------
__global__ __launch_bounds__(192) void qkv_conv_kernel(
    const float* __restrict__ x,
    const float* __restrict__ wq, const float* __restrict__ wk,
    const float* __restrict__ wv, float* __restrict__ qpart)
{
  __shared__ float ws[48 * 145];                 // 27840 B
  __shared__ alignas(16) float xs[3 * 16 * 52];  // 9984 B
  const int y = blockIdx.x;
  const int half = blockIdx.y;
  const int cig = blockIdx.z;          // 16 ci per group
  const int tid = threadIdx.x;
  for (int idx = tid; idx < 3 * 16 * 50; idx += 192) {
    int ky = idx / (16 * 50);
    int r = idx - ky * (16 * 50);
    int cil = r / 50;
    int xx = r - cil * 50;
    int gy = y + ky - 1;
    int gx = xx - 1;
    float v = 0.0f;
    if (gy >= 0 && gy < H && (unsigned)gx < (unsigned)W)
      v = x[(cig * 16 + cil) * HW + gy * W + gx];
    xs[(ky * 16 + cil) * 52 + xx] = v;
  }
  for (int idx = tid; idx < 48 * 144; idx += 192) {
    const int cl_loc = idx / 144;
    const int e = idx - cl_loc * 144;     // ci_local*9 + tap
    const int cog = half * 48 + cl_loc;
    const int t = cog >> 5;
    const int cl = cog & 31;
    const float* wsel = (t == 0) ? wq : (t == 1) ? wk : wv;
    ws[cl_loc * 145 + e] = wsel[cl * (CIN * 9) + cig * 144 + e];
  }
  __syncthreads();

  const int col = tid >> 2;        // 0..47
  const int xg = tid & 3;          // 0..3
  const int cog = half * 48 + col;
  const float* wrowb = &ws[col * 145];

  float acc[12];
#pragma unroll
  for (int i = 0; i < 12; ++i) acc[i] = 0.0f;

#pragma unroll 4
  for (int cil = 0; cil < 16; ++cil) {
#pragma unroll
    for (int ky = 0; ky < 3; ++ky) {
      const float4* p4 =
          reinterpret_cast<const float4*>(&xs[(ky * 16 + cil) * 52 + xg * 12]);
      float4 r0 = p4[0], r1 = p4[1], r2 = p4[2], r3 = p4[3];
      float xr[16] = {r0.x, r0.y, r0.z, r0.w, r1.x, r1.y, r1.z, r1.w,
                      r2.x, r2.y, r2.z, r2.w, r3.x, r3.y, r3.z, r3.w};
      const float* wr = wrowb + cil * 9 + ky * 3;
#pragma unroll
      for (int kx = 0; kx < 3; ++kx) {
        float wgt = wr[kx];
#pragma unroll
        for (int xx = 0; xx < 12; ++xx)
          acc[xx] = fmaf(wgt, xr[xx + kx], acc[xx]);
      }
    }
  }

  const int x0 = xg * 12;
  float* dst = &qpart[(size_t)(cig * 96 + cog) * HW + y * W + x0];
#pragma unroll
  for (int xx = 0; xx < 12; ++xx) dst[xx] = acc[xx];
}

// ---------------------------------------------------------------------------
// Kernel 1b: reduce 4 ci-partials, apply bias (+ exp2-domain scale for q),
// write plain q_s / k_s / v_s (32 x 6144). float4 per thread.
// ---------------------------------------------------------------------------
__global__ __launch_bounds__(256) void qkv_reduce_kernel(
    const float* __restrict__ qpart,
    const float* __restrict__ bq, const float* __restrict__ bk,
    const float* __restrict__ bv,
    float* __restrict__ q_s, float* __restrict__ k_s, float* __restrict__ v_s)
{
  const int fidx = blockIdx.x * 256 + threadIdx.x;  // 0..147455 (96ch*1536)
  const int cog = fidx / 1536;
  const int p4 = fidx - cog * 1536;
  const float4* src = reinterpret_cast<const float4*>(qpart) + cog * 1536 + p4;
  float4 s = src[0];
  const float4 s1 = src[96 * 1536], s2 = src[2 * 96 * 1536], s3 = src[3 * 96 * 1536];
  s.x += s1.x + s2.x + s3.x;
  s.y += s1.y + s2.y + s3.y;
  s.z += s1.z + s2.z + s3.z;
  s.w += s1.w + s2.w + s3.w;

  const int cl = cog & 31;
  if (cog < 32) {
    const float b = bq[cl];
    const float c = 0.7213475204444817f;   // 0.5 * log2(e)
    float4 o = {(s.x + b) * c, (s.y + b) * c, (s.z + b) * c, (s.w + b) * c};
    reinterpret_cast<float4*>(q_s)[cl * 1536 + p4] = o;
  } else {
    const float b = (cog < 64) ? bk[cl] : bv[cl];
    float* dst = (cog < 64) ? k_s : v_s;
    float4 o = {s.x + b, s.y + b, s.z + b, s.w + b};
    reinterpret_cast<float4*>(dst)[cl * 1536 + p4] = o;
  }
}

// ---------------------------------------------------------------------------
// Kernel 1c: materialize the as_strided flange gather ONCE into packed
// kvi[n][m] = {k4, v4}. Zero-padding handled here (no padded buffers).
// grid (45, 16) x 128 threads; thread = one (n, m).
// ---------------------------------------------------------------------------
__global__ __launch_bounds__(128) void kv_pack_kernel(
    const float* __restrict__ k_s, const float* __restrict__ v_s,
    float4* __restrict__ kvi)
{
  const int m = blockIdx.x * 128 + threadIdx.x;   // 0..5759
  const int n = blockIdx.y;
  const int h = n >> 1;
  const int j = n & 1;
  const int m0 = m / 40;
  const int m1 = m - m0 * 40;
  const int base = h * 24576 + j * 24 + m0 * 48 + m1;
  float k4[4], v4[4];
#pragma unroll
  for (int d = 0; d < 4; ++d) {
    const int F = base + d * 6144;       // flat idx into (32,144,64) view
    const int c = F / 9216;
    const int rem = F - c * 9216;
    const int yy = rem >> 6;
    const int xx = rem & 63;
    const bool ok = (yy >= 8 && yy < 136 && xx >= 8 && xx < 56);
    const int src = c * HW + (yy - 8) * W + (xx - 8);
    k4[d] = ok ? k_s[src] : 0.0f;
    v4[d] = ok ? v_s[src] : 0.0f;
  }
  const size_t o = ((size_t)n * KVLEN + m) * 2;
  kvi[o + 0] = make_float4(k4[0], k4[1], k4[2], k4[3]);
  kvi[o + 1] = make_float4(v4[0], v4[1], v4[2], v4[3]);
}

// ---------------------------------------------------------------------------
// Kernel 2: blocked local attention. kv elements are wave-uniform -> read at
// uniform (readfirstlane-pinned) addresses so they come in via s_load into
// SGPRs: zero VALU cost, zero LDS, no broadcast movs. Queries held as f32x2
// pairs; math is v_pk_fma_f32 with the kv SGPR operand. exp2-domain softmax
// with fixed -16 bias (additive partials). grid (12,8,16) x 256, 24 w/CU.
// ---------------------------------------------------------------------------
__global__ __launch_bounds__(256, 6) void attn_kernel(
    const float* __restrict__ q_s, const float4* __restrict__ kvi,
    float* __restrict__ part)
{
  __shared__ float smem[4 * QG * 5];   // 20480 B merge buffer
  const int tid = threadIdx.x;
  const int lane = tid & 63;
  const int wu = __builtin_amdgcn_readfirstlane(tid >> 6);  // uniform wave id
  const int qgrp = blockIdx.x;   // 0..11
  const int sgrp = blockIdx.y;   // 0..7
  const int n = blockIdx.z;      // 0..15
  const int h = n >> 1;
  const int j = n & 1;

  // 2 query-pairs per lane: q2[p][d] = (q_{2p}[d], q_{2p+1}[d])
  f32x2 q2[2][4];
#pragma unroll
  for (int p = 0; p < 2; ++p) {
#pragma unroll
    for (int e = 0; e < 2; ++e) {
      const int qg = qgrp * QG + (2 * p + e) * 64 + lane;
      const int q0 = qg / 24;
      const int q1 = qg - q0 * 24;
      const int qoff = q0 * W + j * 24 + q1;
#pragma unroll
      for (int d = 0; d < 4; ++d)
        q2[p][d][e] = q_s[(h * 4 + d) * HW + qoff];
    }
  }

  // wave's kv slice, uniform base -> scalar loads
  const float4* kvn = kvi + ((size_t)n * KVLEN + (sgrp * 4 + wu) * KVW) * 2;

  f32x2 lsum[2];
  f32x2 acc[2][4];
#pragma unroll
  for (int p = 0; p < 2; ++p) {
    lsum[p] = (f32x2){0.0f, 0.0f};
#pragma unroll
    for (int d = 0; d < 4; ++d) acc[p][d] = (f32x2){0.0f, 0.0f};
  }
  const f32x2 bias2 = {-16.0f, -16.0f};

#pragma unroll 2
  for (int mt = 0; mt < KVW; ++mt) {
    const float4 k4 = kvn[2 * mt];       // uniform -> SGPR (s_load_dwordx4)
    const float4 v4 = kvn[2 * mt + 1];
#pragma unroll
    for (int p = 0; p < 2; ++p) {
      f32x2 s2 = __builtin_elementwise_fma(q2[p][0], (f32x2){k4.x, k4.x}, bias2);
      s2 = __builtin_elementwise_fma(q2[p][1], (f32x2){k4.y, k4.y}, s2);
      s2 = __builtin_elementwise_fma(q2[p][2], (f32x2){k4.z, k4.z}, s2);
      s2 = __builtin_elementwise_fma(q2[p][3], (f32x2){k4.w, k4.w}, s2);
      f32x2 p2;
      p2.x = fexp2(s2.x);
      p2.y = fexp2(s2.y);
      lsum[p] += p2;
      acc[p][0] = __builtin_elementwise_fma(p2, (f32x2){v4.x, v4.x}, acc[p][0]);
      acc[p][1] = __builtin_elementwise_fma(p2, (f32x2){v4.y, v4.y}, acc[p][1]);
      acc[p][2] = __builtin_elementwise_fma(p2, (f32x2){v4.z, v4.z}, acc[p][2]);
      acc[p][3] = __builtin_elementwise_fma(p2, (f32x2){v4.w, v4.w}, acc[p][3]);
    }
  }

  // in-block merge: 4 waves -> 1 partial set (non-atomic global write)
#pragma unroll
  for (int p = 0; p < 2; ++p) {
#pragma unroll
    for (int e = 0; e < 2; ++e) {
      float* mb = &smem[wu * (QG * 5) + (2 * p + e) * 5 * 64 + lane];
      mb[0]   = lsum[p][e];
      mb[64]  = acc[p][0][e];
      mb[128] = acc[p][1][e];
      mb[192] = acc[p][2][e];
      mb[256] = acc[p][3][e];
    }
  }
  __syncthreads();
  float* pout = part + (size_t)((n * NQG + qgrp) * SG + sgrp) * (QG * 5);
  for (int id = tid; id < QG * 5; id += 256)
    pout[id] = smem[id] + smem[QG * 5 + id] + smem[2 * QG * 5 + id] +
               smem[3 * QG * 5 + id];
}

// ---------------------------------------------------------------------------
// Kernel 2b: merge SG slice-group partials + normalize -> o_mid.
// grid (12, 16) x 256 threads; thread = one query.
// ---------------------------------------------------------------------------
__global__ __launch_bounds__(256) void merge_kernel(
    const float* __restrict__ part, float* __restrict__ o_mid)
{
  const int tid = threadIdx.x;
  const int qi = tid >> 6;
  const int lane = tid & 63;
  const int qgrp = blockIdx.x;
  const int n = blockIdx.y;
  const int h = n >> 1;
  const int j = n & 1;

  const float* pb = part + (size_t)((n * NQG + qgrp) * SG) * (QG * 5) +
                    qi * 5 * 64 + lane;
  float L = 0.0f, A0 = 0.0f, A1 = 0.0f, A2 = 0.0f, A3 = 0.0f;
#pragma unroll
  for (int s = 0; s < SG; ++s) {
    const float* p = pb + s * (QG * 5);
    L  += p[0];
    A0 += p[64];
    A1 += p[128];
    A2 += p[192];
    A3 += p[256];
  }
  const float inv = 1.0f / L;
  const int qg = qgrp * QG + qi * 64 + lane;
  const int q0 = qg / 24;
  const int q1 = qg - q0 * 24;
  const int qoff = q0 * W + j * 24 + q1;
  o_mid[(h * 4 + 0) * HW + qoff] = A0 * inv;
  o_mid[(h * 4 + 1) * HW + qoff] = A1 * inv;
  o_mid[(h * 4 + 2) * HW + qoff] = A2 * inv;
  o_mid[(h * 4 + 3) * HW + qoff] = A3 * inv;
}

// ---------------------------------------------------------------------------
// Kernel 3: output 3x3 conv (32->64 ch), ci split 4-ways, weights in LDS
// stride 73 (conflict-free). grid (128,2,4) x 128 threads.
// ---------------------------------------------------------------------------
__global__ __launch_bounds__(128) void out_conv_kernel(
    const float* __restrict__ o_mid, const float* __restrict__ wo,
    float* __restrict__ opart)
{
  __shared__ float ws[32 * 73];                  // 9344 B
  __shared__ alignas(16) float xs[3 * 8 * 52];   // 4992 B
  const int y = blockIdx.x;
  const int half = blockIdx.y;
  const int cig = blockIdx.z;          // 8 ci per group
  const int tid = threadIdx.x;
  for (int idx = tid; idx < 3 * 8 * 50; idx += 128) {
    int ky = idx / (8 * 50);
    int r = idx - ky * (8 * 50);
    int cil = r / 50;
    int xx = r - cil * 50;
    int gy = y + ky - 1;
    int gx = xx - 1;
    float v = 0.0f;
    if (gy >= 0 && gy < H && (unsigned)gx < (unsigned)W)
      v = o_mid[(cig * 8 + cil) * HW + gy * W + gx];
    xs[(ky * 8 + cil) * 52 + xx] = v;
  }
  for (int idx = tid; idx < 32 * 72; idx += 128) {
    const int co_loc = idx / 72;
    const int e = idx - co_loc * 72;
    ws[co_loc * 73 + e] = wo[(half * 32 + co_loc) * (CMID * 9) + cig * 72 + e];
  }
  __syncthreads();

  const int col = tid >> 2;
  const int xg = tid & 3;
  const int co = half * 32 + col;
  const float* wrowb = &ws[col * 73];
  float acc[12];
#pragma unroll
  for (int i = 0; i < 12; ++i) acc[i] = 0.0f;

#pragma unroll 2
  for (int cil = 0; cil < 8; ++cil) {
#pragma unroll
    for (int ky = 0; ky < 3; ++ky) {
      const float4* p4 =
          reinterpret_cast<const float4*>(&xs[(ky * 8 + cil) * 52 + xg * 12]);
      float4 r0 = p4[0], r1 = p4[1], r2 = p4[2], r3 = p4[3];
      float xr[16] = {r0.x, r0.y, r0.z, r0.w, r1.x, r1.y, r1.z, r1.w,
                      r2.x, r2.y, r2.z, r2.w, r3.x, r3.y, r3.z, r3.w};
      const float* wr = wrowb + cil * 9 + ky * 3;
#pragma unroll
      for (int kx = 0; kx < 3; ++kx) {
        float wgt = wr[kx];
#pragma unroll
        for (int xx = 0; xx < 12; ++xx)
          acc[xx] = fmaf(wgt, xr[xx + kx], acc[xx]);
      }
    }
  }

  const int x0 = xg * 12;
  float* dst = &opart[(size_t)(cig * 64 + co) * HW + y * W + x0];
#pragma unroll
  for (int xx = 0; xx < 12; ++xx) dst[xx] = acc[xx];
}

// ---------------------------------------------------------------------------
// Kernel 3b: reduce 4 out-conv partials -> final output. float4 per thread.
// ---------------------------------------------------------------------------
__global__ __launch_bounds__(256) void out_reduce_kernel(
    const float* __restrict__ opart, float* __restrict__ out)
{
  const int fidx = blockIdx.x * 256 + threadIdx.x;  // 0..98303 (64ch*1536)
  const float4* src = reinterpret_cast<const float4*>(opart) + fidx;
  float4 s = src[0];
  const float4 s1 = src[64 * 1536], s2 = src[2 * 64 * 1536], s3 = src[3 * 64 * 1536];
  s.x += s1.x + s2.x + s3.x;
  s.y += s1.y + s2.y + s3.y;
  s.z += s1.z + s2.z + s3.z;
  s.w += s1.w + s2.w + s3.w;
  reinterpret_cast<float4*>(out)[fidx] = s;
}

// ---------------------------------------------------------------------------
extern "C" void kernel_launch(void* const* d_in, const int* in_sizes, int n_in,
                              void* d_out, int out_size, void* d_ws, size_t ws_size,
                              hipStream_t stream) {
  const float* x  = (const float*)d_in[0];
  const float* wq = (const float*)d_in[1];
  const float* bq = (const float*)d_in[2];
  const float* wk = (const float*)d_in[3];
  const float* bk = (const float*)d_in[4];
  const float* wv = (const float*)d_in[5];
  const float* bv = (const float*)d_in[6];
  const float* wo = (const float*)d_in[7];
  float* out = (float*)d_out;

  // ws layout (floats): q_s | k_s | v_s | o_mid | kvi | part | qpart(=opart)
  float* q_s   = (float*)d_ws;
  float* k_s   = q_s + QSSZ;
  float* v_s   = k_s + QSSZ;
  float* o_mid = v_s + QSSZ;
  float* kvi   = o_mid + QSSZ;
  float* part  = kvi + KVISZ;
  float* qpart = part + PARTSZ;
  float* opart = qpart;   // phases are stream-ordered; safe alias

  qkv_conv_kernel<<<dim3(128, 2, CIGQ), 192, 0, stream>>>(x, wq, wk, wv, qpart);
  qkv_reduce_kernel<<<dim3(576), 256, 0, stream>>>(qpart, bq, bk, bv,
                                                   q_s, k_s, v_s);
  kv_pack_kernel<<<dim3(45, 16), 128, 0, stream>>>(k_s, v_s, (float4*)kvi);
  attn_kernel<<<dim3(NQG, SG, 16), 256, 0, stream>>>(q_s, (const float4*)kvi,
                                                     part);
  merge_kernel<<<dim3(NQG, 16), 256, 0, stream>>>(part, o_mid);
  out_conv_kernel<<<dim3(128, 2, CIGO), 128, 0, stream>>>(o_mid, wo, opart);
  out_reduce_kernel<<<dim3(384), 256, 0, stream>>>(opart, out);
}

// Round 9
// 188.554 us; speedup vs baseline: 1.0927x; 1.0329x over previous
//
#include <hip/hip_runtime.h>
#include <hip/hip_bf16.h>

typedef float f32x2 __attribute__((ext_vector_type(2)));

namespace {
enum : int {
  CIN = 64, CMID = 32, COUT = 64,
  H = 128, W = 48, HW = H * W,          // 6144
  QSSZ = CMID * HW,                     // 196608 floats
  // attention tiling
  QPT = 8,                              // queries per lane (4 f32x2 pairs)
  QG  = 64 * QPT,                       // 512 queries per block
  NQG = 6,                              // 3072/512 query groups per n
  KVW = 180,                            // kv elems per wave
  SG  = 8,                              // slice groups along kv (8*4*180=5760)
  KVLEN = 5760,
  PARTSZ = 16 * NQG * SG * QG * 5,      // 1,966,080 floats
  KVISZ = 16 * KVLEN * 8,               // 737,280 floats (packed k4|v4)
  CIGQ = 4, CIGO = 4,
};
}

__device__ __forceinline__ float fexp2(float x) { return __builtin_amdgcn_exp2f(x); }

// ---------------------------------------------------------------------------
// Kernel 1: q/k/v 3x3 convs (64->32 ch), ci split 4-ways, weights staged in
// LDS with stride 145 (bank-conflict-free). grid (128,2,4) x 192.
// ---------------------------------------------------------------------------
__global__ __launch_bounds__(192) void qkv_conv_kernel(
    const float* __restrict__ x,
    const float* __restrict__ wq, const float* __restrict__ wk,
    const float* __restrict__ wv, float* __restrict__ qpart)
{
  __shared__ float ws[48 * 145];                 // 27840 B
  __shared__ alignas(16) float xs[3 * 16 * 52];  // 9984 B
  const int y = blockIdx.x;
  const int half = blockIdx.y;
  const int cig = blockIdx.z;          // 16 ci per group
  const int tid = threadIdx.x;
  for (int idx = tid; idx < 3 * 16 * 50; idx += 192) {
    int ky = idx / (16 * 50);
    int r = idx - ky * (16 * 50);
    int cil = r / 50;
    int xx = r - cil * 50;
    int gy = y + ky - 1;
    int gx = xx - 1;
    float v = 0.0f;
    if (gy >= 0 && gy < H && (unsigned)gx < (unsigned)W)
      v = x[(cig * 16 + cil) * HW + gy * W + gx];
    xs[(ky * 16 + cil) * 52 + xx] = v;
  }
  for (int idx = tid; idx < 48 * 144; idx += 192) {
    const int cl_loc = idx / 144;
    const int e = idx - cl_loc * 144;     // ci_local*9 + tap
    const int cog = half * 48 + cl_loc;
    const int t = cog >> 5;
    const int cl = cog & 31;
    const float* wsel = (t == 0) ? wq : (t == 1) ? wk : wv;
    ws[cl_loc * 145 + e] = wsel[cl * (CIN * 9) + cig * 144 + e];
  }
  __syncthreads();

  const int col = tid >> 2;        // 0..47
  const int xg = tid & 3;          // 0..3
  const int cog = half * 48 + col;
  const float* wrowb = &ws[col * 145];

  float acc[12];
#pragma unroll
  for (int i = 0; i < 12; ++i) acc[i] = 0.0f;

#pragma unroll 4
  for (int cil = 0; cil < 16; ++cil) {
#pragma unroll
    for (int ky = 0; ky < 3; ++ky) {
      const float4* p4 =
          reinterpret_cast<const float4*>(&xs[(ky * 16 + cil) * 52 + xg * 12]);
      float4 r0 = p4[0], r1 = p4[1], r2 = p4[2], r3 = p4[3];
      float xr[16] = {r0.x, r0.y, r0.z, r0.w, r1.x, r1.y, r1.z, r1.w,
                      r2.x, r2.y, r2.z, r2.w, r3.x, r3.y, r3.z, r3.w};
      const float* wr = wrowb + cil * 9 + ky * 3;
#pragma unroll
      for (int kx = 0; kx < 3; ++kx) {
        float wgt = wr[kx];
#pragma unroll
        for (int xx = 0; xx < 12; ++xx)
          acc[xx] = fmaf(wgt, xr[xx + kx], acc[xx]);
      }
    }
  }

  const int x0 = xg * 12;
  float* dst = &qpart[(size_t)(cig * 96 + cog) * HW + y * W + x0];
#pragma unroll
  for (int xx = 0; xx < 12; ++xx) dst[xx] = acc[xx];
}

// ---------------------------------------------------------------------------
// Kernel 1b: reduce 4 ci-partials, apply bias (+ exp2-domain scale for q),
// write plain q_s / k_s / v_s (32 x 6144). float4 per thread.
// ---------------------------------------------------------------------------
__global__ __launch_bounds__(256) void qkv_reduce_kernel(
    const float* __restrict__ qpart,
    const float* __restrict__ bq, const float* __restrict__ bk,
    const float* __restrict__ bv,
    float* __restrict__ q_s, float* __restrict__ k_s, float* __restrict__ v_s)
{
  const int fidx = blockIdx.x * 256 + threadIdx.x;  // 0..147455 (96ch*1536)
  const int cog = fidx / 1536;
  const int p4 = fidx - cog * 1536;
  const float4* src = reinterpret_cast<const float4*>(qpart) + cog * 1536 + p4;
  float4 s = src[0];
  const float4 s1 = src[96 * 1536], s2 = src[2 * 96 * 1536], s3 = src[3 * 96 * 1536];
  s.x += s1.x + s2.x + s3.x;
  s.y += s1.y + s2.y + s3.y;
  s.z += s1.z + s2.z + s3.z;
  s.w += s1.w + s2.w + s3.w;

  const int cl = cog & 31;
  if (cog < 32) {
    const float b = bq[cl];
    const float c = 0.7213475204444817f;   // 0.5 * log2(e)
    float4 o = {(s.x + b) * c, (s.y + b) * c, (s.z + b) * c, (s.w + b) * c};
    reinterpret_cast<float4*>(q_s)[cl * 1536 + p4] = o;
  } else {
    const float b = (cog < 64) ? bk[cl] : bv[cl];
    float* dst = (cog < 64) ? k_s : v_s;
    float4 o = {s.x + b, s.y + b, s.z + b, s.w + b};
    reinterpret_cast<float4*>(dst)[cl * 1536 + p4] = o;
  }
}

// ---------------------------------------------------------------------------
// Kernel 1c: materialize the as_strided flange gather ONCE into packed
// kvi[n][m] = {k4, v4}. Zero-padding handled here.
// grid (45, 16) x 128 threads; thread = one (n, m).
// ---------------------------------------------------------------------------
__global__ __launch_bounds__(128) void kv_pack_kernel(
    const float* __restrict__ k_s, const float* __restrict__ v_s,
    float4* __restrict__ kvi)
{
  const int m = blockIdx.x * 128 + threadIdx.x;   // 0..5759
  const int n = blockIdx.y;
  const int h = n >> 1;
  const int j = n & 1;
  const int m0 = m / 40;
  const int m1 = m - m0 * 40;
  const int base = h * 24576 + j * 24 + m0 * 48 + m1;
  float k4[4], v4[4];
#pragma unroll
  for (int d = 0; d < 4; ++d) {
    const int F = base + d * 6144;       // flat idx into (32,144,64) view
    const int c = F / 9216;
    const int rem = F - c * 9216;
    const int yy = rem >> 6;
    const int xx = rem & 63;
    const bool ok = (yy >= 8 && yy < 136 && xx >= 8 && xx < 56);
    const int src = c * HW + (yy - 8) * W + (xx - 8);
    k4[d] = ok ? k_s[src] : 0.0f;
    v4[d] = ok ? v_s[src] : 0.0f;
  }
  const size_t o = ((size_t)n * KVLEN + m) * 2;
  kvi[o + 0] = make_float4(k4[0], k4[1], k4[2], k4[3]);
  kvi[o + 1] = make_float4(v4[0], v4[1], v4[2], v4[3]);
}

// ---------------------------------------------------------------------------
// Kernel 2: blocked local attention. Per-wave kv slice staged into LDS from
// the packed kvi (coalesced float4 copies), inner loop = wave-uniform
// ds_read_b128 broadcast (conflict-free, short latency) + packed-fp32 math
// over 8 queries/lane (4 f32x2 pairs). exp2-domain softmax, fixed -16 bias,
// additive partials. Flat grid 768, XCD-swizzled: blocks with bid%8==xcd
// handle n in {2*xcd, 2*xcd+1} (same head pair) -> per-XCD L2 working set
// ~470 KB instead of the whole kvi. launch_bounds(256,4): VGPR<=128, no
// AGPR spill (round-8's VGPR=24 pathology), 16 waves/CU.
// ---------------------------------------------------------------------------
__global__ __launch_bounds__(256, 4) void attn_kernel(
    const float* __restrict__ q_s, const float4* __restrict__ kvi,
    float* __restrict__ part)
{
  __shared__ alignas(16) float smem[4 * QG * 5];   // 40960 B (tiles alias)
  float4* tiles = reinterpret_cast<float4*>(smem); // [4][2*KVW]

  const int tid = threadIdx.x;
  const int lane = tid & 63;
  const int wu = __builtin_amdgcn_readfirstlane(tid >> 6);
  // XCD swizzle: round-robin dispatch puts bid%8 on XCD (bid%8)
  const int bid = blockIdx.x;          // 0..767
  const int xcd = bid & 7;
  const int li = bid >> 3;             // 0..95
  const int n = xcd * 2 + (li / 48);   // 0..15, 2 n per XCD (same head)
  const int r = li % 48;
  const int qgrp = r % 6;              // 0..5
  const int sgrp = r / 6;              // 0..7
  const int h = n >> 1;
  const int j = n & 1;

  // 4 query-pairs per lane: q2[p][d] = (q_{2p}[d], q_{2p+1}[d])
  f32x2 q2[4][4];
#pragma unroll
  for (int p = 0; p < 4; ++p) {
#pragma unroll
    for (int e = 0; e < 2; ++e) {
      const int qg = qgrp * QG + (2 * p + e) * 64 + lane;
      const int q0 = qg / 24;
      const int q1 = qg - q0 * 24;
      const int qoff = q0 * W + j * 24 + q1;
#pragma unroll
      for (int d = 0; d < 4; ++d)
        q2[p][d][e] = q_s[(h * 4 + d) * HW + qoff];
    }
  }

  // stage this wave's kv slice into LDS (coalesced; kvi already packed)
  const float4* kvn = kvi + ((size_t)n * KVLEN + (sgrp * 4 + wu) * KVW) * 2;
  float4* tile = tiles + wu * (2 * KVW);
  for (int idx = lane; idx < 2 * KVW; idx += 64)
    tile[idx] = kvn[idx];
  asm volatile("s_waitcnt vmcnt(0) lgkmcnt(0)" ::: "memory");

  f32x2 lsum[4];
  f32x2 acc[4][4];
#pragma unroll
  for (int p = 0; p < 4; ++p) {
    lsum[p] = (f32x2){0.0f, 0.0f};
#pragma unroll
    for (int d = 0; d < 4; ++d) acc[p][d] = (f32x2){0.0f, 0.0f};
  }
  const f32x2 bias2 = {-16.0f, -16.0f};

#pragma unroll 2
  for (int mt = 0; mt < KVW; ++mt) {
    const float4 k4 = tile[2 * mt];      // uniform addr -> LDS broadcast
    const float4 v4 = tile[2 * mt + 1];
#pragma unroll
    for (int p = 0; p < 4; ++p) {
      f32x2 s2 = __builtin_elementwise_fma(q2[p][0], (f32x2){k4.x, k4.x}, bias2);
      s2 = __builtin_elementwise_fma(q2[p][1], (f32x2){k4.y, k4.y}, s2);
      s2 = __builtin_elementwise_fma(q2[p][2], (f32x2){k4.z, k4.z}, s2);
      s2 = __builtin_elementwise_fma(q2[p][3], (f32x2){k4.w, k4.w}, s2);
      f32x2 p2;
      p2.x = fexp2(s2.x);
      p2.y = fexp2(s2.y);
      lsum[p] += p2;
      acc[p][0] = __builtin_elementwise_fma(p2, (f32x2){v4.x, v4.x}, acc[p][0]);
      acc[p][1] = __builtin_elementwise_fma(p2, (f32x2){v4.y, v4.y}, acc[p][1]);
      acc[p][2] = __builtin_elementwise_fma(p2, (f32x2){v4.z, v4.z}, acc[p][2]);
      acc[p][3] = __builtin_elementwise_fma(p2, (f32x2){v4.w, v4.w}, acc[p][3]);
    }
  }

  // tiles region is inside other waves' merge sections -> barrier first
  __syncthreads();
#pragma unroll
  for (int p = 0; p < 4; ++p) {
#pragma unroll
    for (int e = 0; e < 2; ++e) {
      float* mb = &smem[wu * (QG * 5) + (2 * p + e) * 5 * 64 + lane];
      mb[0]   = lsum[p][e];
      mb[64]  = acc[p][0][e];
      mb[128] = acc[p][1][e];
      mb[192] = acc[p][2][e];
      mb[256] = acc[p][3][e];
    }
  }
  __syncthreads();
  float* pout = part + (size_t)((n * NQG + qgrp) * SG + sgrp) * (QG * 5);
  for (int id = tid; id < QG * 5; id += 256)
    pout[id] = smem[id] + smem[QG * 5 + id] + smem[2 * QG * 5 + id] +
               smem[3 * QG * 5 + id];
}

// ---------------------------------------------------------------------------
// Kernel 2b: merge SG slice-group partials + normalize -> o_mid.
// grid (NQG, 16) x 512 threads; thread = one query.
// ---------------------------------------------------------------------------
__global__ __launch_bounds__(512) void merge_kernel(
    const float* __restrict__ part, float* __restrict__ o_mid)
{
  const int tid = threadIdx.x;
  const int qi = tid >> 6;      // 0..7
  const int lane = tid & 63;
  const int qgrp = blockIdx.x;
  const int n = blockIdx.y;
  const int h = n >> 1;
  const int j = n & 1;

  const float* pb = part + (size_t)((n * NQG + qgrp) * SG) * (QG * 5) +
                    qi * 5 * 64 + lane;
  float L = 0.0f, A0 = 0.0f, A1 = 0.0f, A2 = 0.0f, A3 = 0.0f;
#pragma unroll
  for (int s = 0; s < SG; ++s) {
    const float* p = pb + s * (QG * 5);
    L  += p[0];
    A0 += p[64];
    A1 += p[128];
    A2 += p[192];
    A3 += p[256];
  }
  const float inv = 1.0f / L;
  const int qg = qgrp * QG + qi * 64 + lane;
  const int q0 = qg / 24;
  const int q1 = qg - q0 * 24;
  const int qoff = q0 * W + j * 24 + q1;
  o_mid[(h * 4 + 0) * HW + qoff] = A0 * inv;
  o_mid[(h * 4 + 1) * HW + qoff] = A1 * inv;
  o_mid[(h * 4 + 2) * HW + qoff] = A2 * inv;
  o_mid[(h * 4 + 3) * HW + qoff] = A3 * inv;
}

// ---------------------------------------------------------------------------
// Kernel 3: output 3x3 conv (32->64 ch), ci split 4-ways, weights in LDS
// stride 73 (conflict-free). grid (128,2,4) x 128 threads.
// ---------------------------------------------------------------------------
__global__ __launch_bounds__(128) void out_conv_kernel(
    const float* __restrict__ o_mid, const float* __restrict__ wo,
    float* __restrict__ opart)
{
  __shared__ float ws[32 * 73];                  // 9344 B
  __shared__ alignas(16) float xs[3 * 8 * 52];   // 4992 B
  const int y = blockIdx.x;
  const int half = blockIdx.y;
  const int cig = blockIdx.z;          // 8 ci per group
  const int tid = threadIdx.x;
  for (int idx = tid; idx < 3 * 8 * 50; idx += 128) {
    int ky = idx / (8 * 50);
    int r = idx - ky * (8 * 50);
    int cil = r / 50;
    int xx = r - cil * 50;
    int gy = y + ky - 1;
    int gx = xx - 1;
    float v = 0.0f;
    if (gy >= 0 && gy < H && (unsigned)gx < (unsigned)W)
      v = o_mid[(cig * 8 + cil) * HW + gy * W + gx];
    xs[(ky * 8 + cil) * 52 + xx] = v;
  }
  for (int idx = tid; idx < 32 * 72; idx += 128) {
    const int co_loc = idx / 72;
    const int e = idx - co_loc * 72;
    ws[co_loc * 73 + e] = wo[(half * 32 + co_loc) * (CMID * 9) + cig * 72 + e];
  }
  __syncthreads();

  const int col = tid >> 2;
  const int xg = tid & 3;
  const int co = half * 32 + col;
  const float* wrowb = &ws[col * 73];
  float acc[12];
#pragma unroll
  for (int i = 0; i < 12; ++i) acc[i] = 0.0f;

#pragma unroll 2
  for (int cil = 0; cil < 8; ++cil) {
#pragma unroll
    for (int ky = 0; ky < 3; ++ky) {
      const float4* p4 =
          reinterpret_cast<const float4*>(&xs[(ky * 8 + cil) * 52 + xg * 12]);
      float4 r0 = p4[0], r1 = p4[1], r2 = p4[2], r3 = p4[3];
      float xr[16] = {r0.x, r0.y, r0.z, r0.w, r1.x, r1.y, r1.z, r1.w,
                      r2.x, r2.y, r2.z, r2.w, r3.x, r3.y, r3.z, r3.w};
      const float* wr = wrowb + cil * 9 + ky * 3;
#pragma unroll
      for (int kx = 0; kx < 3; ++kx) {
        float wgt = wr[kx];
#pragma unroll
        for (int xx = 0; xx < 12; ++xx)
          acc[xx] = fmaf(wgt, xr[xx + kx], acc[xx]);
      }
    }
  }

  const int x0 = xg * 12;
  float* dst = &opart[(size_t)(cig * 64 + co) * HW + y * W + x0];
#pragma unroll
  for (int xx = 0; xx < 12; ++xx) dst[xx] = acc[xx];
}

// ---------------------------------------------------------------------------
// Kernel 3b: reduce 4 out-conv partials -> final output. float4 per thread.
// ---------------------------------------------------------------------------
__global__ __launch_bounds__(256) void out_reduce_kernel(
    const float* __restrict__ opart, float* __restrict__ out)
{
  const int fidx = blockIdx.x * 256 + threadIdx.x;  // 0..98303 (64ch*1536)
  const float4* src = reinterpret_cast<const float4*>(opart) + fidx;
  float4 s = src[0];
  const float4 s1 = src[64 * 1536], s2 = src[2 * 64 * 1536], s3 = src[3 * 64 * 1536];
  s.x += s1.x + s2.x + s3.x;
  s.y += s1.y + s2.y + s3.y;
  s.z += s1.z + s2.z + s3.z;
  s.w += s1.w + s2.w + s3.w;
  reinterpret_cast<float4*>(out)[fidx] = s;
}

// ---------------------------------------------------------------------------
extern "C" void kernel_launch(void* const* d_in, const int* in_sizes, int n_in,
                              void* d_out, int out_size, void* d_ws, size_t ws_size,
                              hipStream_t stream) {
  const float* x  = (const float*)d_in[0];
  const float* wq = (const float*)d_in[1];
  const float* bq = (const float*)d_in[2];
  const float* wk = (const float*)d_in[3];
  const float* bk = (const float*)d_in[4];
  const float* wv = (const float*)d_in[5];
  const float* bv = (const float*)d_in[6];
  const float* wo = (const float*)d_in[7];
  float* out = (float*)d_out;

  // ws layout (floats): q_s | k_s | v_s | o_mid | kvi | part | qpart(=opart)
  float* q_s   = (float*)d_ws;
  float* k_s   = q_s + QSSZ;
  float* v_s   = k_s + QSSZ;
  float* o_mid = v_s + QSSZ;
  float* kvi   = o_mid + QSSZ;
  float* part  = kvi + KVISZ;
  float* qpart = part + PARTSZ;
  float* opart = qpart;   // phases are stream-ordered; safe alias

  qkv_conv_kernel<<<dim3(128, 2, CIGQ), 192, 0, stream>>>(x, wq, wk, wv, qpart);
  qkv_reduce_kernel<<<dim3(576), 256, 0, stream>>>(qpart, bq, bk, bv,
                                                   q_s, k_s, v_s);
  kv_pack_kernel<<<dim3(45, 16), 128, 0, stream>>>(k_s, v_s, (float4*)kvi);
  attn_kernel<<<dim3(768), 256, 0, stream>>>(q_s, (const float4*)kvi, part);
  merge_kernel<<<dim3(NQG, 16), 512, 0, stream>>>(part, o_mid);
  out_conv_kernel<<<dim3(128, 2, CIGO), 128, 0, stream>>>(o_mid, wo, opart);
  out_reduce_kernel<<<dim3(384), 256, 0, stream>>>(opart, out);
}